// Round 9
// baseline (4660.144 us; speedup 1.0000x reference)
//
#include <hip/hip_runtime.h>
#include <cstdint>
#include <cstddef>

typedef _Float16 half_t;
typedef half_t half2_t __attribute__((ext_vector_type(2)));

static constexpr int TTs = 2048;   // timesteps
static constexpr int BBn = 64;     // batch
static constexpr int DINn = 64;    // input dim
static constexpr int HPn  = 256;   // proj dim
static constexpr int U0c = 135, C0c = 391, R0c = 405;   // layer0
static constexpr int U1c = 89,  C1c = 224, R1c = 267;   // layer1
static constexpr int U2c = 32,  C2c = 121, R2c = 96;    // layer2
static constexpr size_t BTn = (size_t)BBn * TTs;        // 131072

// ---------------- math helpers ----------------
__device__ __forceinline__ float tanh_f(float x) {
    return 1.f - __fdividef(2.f, __expf(2.f * x) + 1.f);
}
__device__ __forceinline__ float sigm_f(float x) {
    return __fdividef(1.f, 1.f + __expf(-x));
}
__device__ __forceinline__ float cfc_comb(float y0, float y1, float y2) {
    float f1 = tanh_f(y0), f2 = tanh_f(y1), ti = sigm_f(y2);
    return f1 + ti * (f2 - f1);
}
// quad butterfly sum via DPP (VALU pipe, no LDS)
__device__ __forceinline__ float qsum(float v) {
    v += __builtin_bit_cast(float, __builtin_amdgcn_update_dpp(
             0, __builtin_bit_cast(int, v), 0xB1, 0xF, 0xF, true));  // [1,0,3,2]
    v += __builtin_bit_cast(float, __builtin_amdgcn_update_dpp(
             0, __builtin_bit_cast(int, v), 0x4E, 0xF, 0xF, true));  // [2,3,0,1]
    return v;
}
__device__ __forceinline__ half2_t h2(unsigned u) { return __builtin_bit_cast(half2_t, u); }

// ---------------- mask dtype probe ----------------
__device__ __forceinline__ int mask_mode(const unsigned char* mp) {
    const unsigned* wp = (const unsigned*)mp;
    bool all01 = true, allf = true;
    for (int k = 0; k < 64; ++k) {
        unsigned w = wp[k];
        all01 = all01 && (w == 0u || w == 1u);
        allf  = allf  && (w == 0u || w == 0x3F800000u);
    }
    if (all01) return 0;
    if (allf)  return 1;
    return 2;
}
__device__ __forceinline__ bool mget(const unsigned char* mp, int mode, int idx) {
    if (mode == 0) return ((const int*)mp)[idx] != 0;
    if (mode == 1) return ((const float*)mp)[idx] != 0.f;
    return mp[idx] != 0;
}

// ---------------- prep: stack + mask weights ----------------
__global__ void k_stack(const float* __restrict__ Wff1, const float* __restrict__ bff1,
                        const float* __restrict__ Wff2, const float* __restrict__ bff2,
                        const float* __restrict__ Wta,  const float* __restrict__ bta,
                        const float* __restrict__ Wtb,  const float* __restrict__ btb,
                        const unsigned char* __restrict__ maskraw,
                        int u, int c, int split,
                        float* __restrict__ outA, float* __restrict__ outB,
                        float* __restrict__ bias_out)
{
    const int mode = mask_mode(maskraw);
    const int total = 3 * u * c + 3 * u;
    for (int idx = blockIdx.x * blockDim.x + threadIdx.x; idx < total;
         idx += gridDim.x * blockDim.x) {
        if (idx < 3 * u * c) {
            int m = idx / (u * c);
            int rem = idx - m * u * c;
            int r = rem / c;
            int k = rem - r * c;
            float v;
            if (m == 2) {
                v = Wta[r * c + k] + Wtb[r * c + k];
            } else {
                bool mk = mget(maskraw, mode, r * c + k);
                float w = (m == 0) ? Wff1[r * c + k] : Wff2[r * c + k];
                v = mk ? w : 0.f;
            }
            int R = m * u + r;
            if (k < split) outA[(size_t)R * split + k] = v;
            else           outB[(size_t)R * (c - split) + (k - split)] = v;
        } else {
            int j = idx - 3 * u * c;
            int m = j / u, r = j - m * u;
            bias_out[j] = (m == 0) ? bff1[r] : ((m == 1) ? bff2[r] : (bta[r] + btb[r]));
        }
    }
}

// ---------------- prep: Wcomb = Wx0s (405x256) @ Wp (256x64) ----------------
__global__ void k_comb(const float* __restrict__ Wx0s, const float* __restrict__ Wp,
                       float* __restrict__ Wcomb)
{
    const int r = blockIdx.x;
    const int d = threadIdx.x;
    float acc = 0.f;
    for (int k = 0; k < HPn; ++k) acc += Wx0s[(size_t)r * HPn + k] * Wp[(size_t)k * DINn + d];
    Wcomb[(size_t)r * DINn + d] = acc;
}

// ---------------- prep: folded bias + Wh2 transpose ----------------
__global__ void k_biasc(const float* __restrict__ Wx0s, const float* __restrict__ bp,
                        const float* __restrict__ b0, float* __restrict__ b0c,
                        const float* __restrict__ Wh2, float* __restrict__ Wh2T)
{
    const int i = blockIdx.x * blockDim.x + threadIdx.x;
    if (i < R0c) {
        float a = b0[i];
        for (int k = 0; k < HPn; ++k) a += Wx0s[(size_t)i * HPn + k] * bp[k];
        b0c[i] = a;
    }
    if (i < HPn * 32) {
        int h = i >> 5, o = i & 31;
        Wh2T[i] = Wh2[(size_t)o * HPn + h];
    }
}

// ---------------- prep: pack weights to padded fp16 ----------------
// W0h (405,224): [Wcb:64 | Wh0s:135 | 0:25]; W1h (267,224); W2h (96,128): [W2s:121|0:7]
__global__ void k_pack(const float* __restrict__ Wcb, const float* __restrict__ Wh0s,
                       const float* __restrict__ W1s, const float* __restrict__ W2s,
                       half_t* __restrict__ W0h, half_t* __restrict__ W1h,
                       half_t* __restrict__ W2h)
{
    const int N0 = R0c * 224, N1 = R1c * 224, N2 = R2c * 128;
    for (int idx = blockIdx.x * blockDim.x + threadIdx.x; idx < N0 + N1 + N2;
         idx += gridDim.x * blockDim.x) {
        if (idx < N0) {
            int r = idx / 224, c = idx - r * 224;
            float v = (c < 64) ? Wcb[(size_t)r * 64 + c]
                               : ((c < 199) ? Wh0s[(size_t)r * 135 + (c - 64)] : 0.f);
            W0h[idx] = (half_t)v;
        } else if (idx < N0 + N1) {
            int i = idx - N0;
            W1h[i] = (half_t)W1s[i];
        } else {
            int i = idx - N0 - N1;
            int r = i / 128, c = i - r * 128;
            W2h[i] = (half_t)((c < 121) ? W2s[(size_t)r * 121 + c] : 0.f);
        }
    }
}

// light barrier: LDS-ordering only; vmem stays in flight.
#define BAR() asm volatile("s_waitcnt lgkmcnt(0)\n\ts_barrier" ::: "memory")

// ---- AGPR storage: weights live in accumulator registers across the loop ----
struct ag4 { unsigned x, y, z, w; };
#define AW(dst, s) asm volatile( \
    "v_accvgpr_write_b32 %0, %4\n\t" \
    "v_accvgpr_write_b32 %1, %5\n\t" \
    "v_accvgpr_write_b32 %2, %6\n\t" \
    "v_accvgpr_write_b32 %3, %7" \
    : "=a"((dst).x), "=a"((dst).y), "=a"((dst).z), "=a"((dst).w) \
    : "v"((s).x), "v"((s).y), "v"((s).z), "v"((s).w));
#define AR(d, s) asm volatile( \
    "v_accvgpr_read_b32 %0, %4\n\t" \
    "v_accvgpr_read_b32 %1, %5\n\t" \
    "v_accvgpr_read_b32 %2, %6\n\t" \
    "v_accvgpr_read_b32 %3, %7" \
    : "=v"((d).x), "=v"((d).y), "=v"((d).z), "=v"((d).w) \
    : "a"((s).x), "a"((s).y), "a"((s).z), "a"((s).w));

#define D4(acc, W, F) \
    acc = __builtin_amdgcn_fdot2(h2((W).x), __builtin_bit_cast(half2_t,(F).x), acc, false); \
    acc = __builtin_amdgcn_fdot2(h2((W).y), __builtin_bit_cast(half2_t,(F).y), acc, false); \
    acc = __builtin_amdgcn_fdot2(h2((W).z), __builtin_bit_cast(half2_t,(F).z), acc, false); \
    acc = __builtin_amdgcn_fdot2(h2((W).w), __builtin_bit_cast(half2_t,(F).w), acc, false);
#define DA4(acc, agw, F) { uint4 _t; AR(_t, agw) D4(acc, _t, F) }
#define DR7A(acc, A,B,C,D,E,F,G) DA4(acc,A,f0) DA4(acc,B,f1) DA4(acc,C,f2) \
    DA4(acc,D,f3) DA4(acc,E,f4) DA4(acc,F,f5) DA4(acc,G,f6)
#define DR4A(acc, A,B,C,D) DA4(acc,A,f0) DA4(acc,B,f1) DA4(acc,C,f2) DA4(acc,D,f3)
// prologue staging: one weight row (7 uint4) loaded then written to AGPRs;
// sched_barrier keeps prologue register pressure at ~28 VGPRs.
#define AW7(w0,w1,w2,w3,w4,w5,w6, ptr, kill) { \
    const uint4* _p = (const uint4*)(ptr); \
    uint4 t0=_p[0],t1=_p[1],t2=_p[2],t3=_p[3],t4=_p[4],t5=_p[5],t6=_p[6]; \
    if (kill) { t0=z4u;t1=z4u;t2=z4u;t3=z4u;t4=z4u;t5=z4u;t6=z4u; } \
    AW(w0,t0) AW(w1,t1) AW(w2,t2) AW(w3,t3) AW(w4,t4) AW(w5,t5) AW(w6,t6) \
    __builtin_amdgcn_sched_barrier(0); }
#define AW4B(w0,w1,w2,w3, ptr) { \
    const uint4* _p = (const uint4*)(ptr); \
    uint4 t0=_p[0],t1=_p[1],t2=_p[2],t3=_p[3]; \
    AW(w0,t0) AW(w1,t1) AW(w2,t2) AW(w3,t3) \
    __builtin_amdgcn_sched_barrier(0); }

// ---------------- pipelined recurrent scan: 64 blocks x 512 threads ----------
// Same schedule as round 8 (verified): iteration k runs L0 | L1 | L2 skewed,
// one light barrier per iteration, double-buffered state. Change: weights are
// AGPR-resident (42 uint4/lane via v_accvgpr_write), read back with
// v_accvgpr_read right before each fdot2 -> no per-iteration L2 re-fetch.
// Wave 7's leftover-L0 weights (21 uint4) live in LDS instead (keeps the
// kernel-wide AGPR count at 168 so arch VGPRs get ~88).
__global__ __launch_bounds__(512) void k_scan(
    const half_t* __restrict__ W0h,   // (405,224)
    const half_t* __restrict__ W1h,   // (267,224)
    const half_t* __restrict__ W2h,   // (96,128)
    const float* __restrict__ b0c,    // (405)
    const float* __restrict__ b1s,    // (267)
    const float* __restrict__ b2s,    // (96)
    const float* __restrict__ x,      // (B,T,64)
    float* __restrict__ cfc)          // (B,T,32)
{
    const int t = threadIdx.x;
    const int b = blockIdx.x;
    const int q = t & 3;

    __shared__ float4 z0v[2][28];   // 224 halfs: [x:64 | h0:135 | 0:25]
    __shared__ float4 z1v[2][28];   // 224 halfs: [h0:135 | h1:89]
    __shared__ float4 z2v[2][16];   // 128 halfs: [h1:89 | h2:32 | 0:7]
    __shared__ uint4  lwv[28][21];  // wave7 leftover-L0 weights (9.4 KB)

    {
        float4* zz = (float4*)z0v;
        for (int i = t; i < 144; i += 512) zz[i] = make_float4(0.f, 0.f, 0.f, 0.f);
    }

    const bool gL0 = (t < 256);
    const bool gL1 = (t >= 256) && (t < 448);
    const int s0 = t >> 2;            // 0..63   (L0)
    const int s1 = (t - 256) >> 2;    // 0..47   (L1)
    const int s2 = (t - 448) >> 2;    // 0..15   (L2)
    const int xi = t - 448;           // wave 7 stages x

    const uint4 z4u = make_uint4(0u, 0u, 0u, 0u);
    // 42 AGPR-resident uint4 (168 dwords). wave7 uses only w00..w23.
    ag4 w00,w01,w02,w03,w04,w05,w06, w07,w08,w09,w10,w11,w12,w13;
    ag4 w14,w15,w16,w17,w18,w19,w20, w21,w22,w23,w24,w25,w26,w27;
    ag4 w28,w29,w30,w31,w32,w33,w34, w35,w36,w37,w38,w39,w40,w41;

    float bA0=0.f,bA1=0.f,bA2=0.f, bB0=0.f,bB1=0.f,bB2=0.f, bX0=0.f,bX1=0.f,bX2=0.f;
    bool vB = false, vX = false;

    if (gL0) {
        const size_t cq = 56 * q;
        AW7(w00,w01,w02,w03,w04,w05,w06, W0h + (size_t)(s0      ) * 224 + cq, false)
        AW7(w07,w08,w09,w10,w11,w12,w13, W0h + (size_t)(s0 + 135) * 224 + cq, false)
        AW7(w14,w15,w16,w17,w18,w19,w20, W0h + (size_t)(s0 + 270) * 224 + cq, false)
        AW7(w21,w22,w23,w24,w25,w26,w27, W0h + (size_t)(s0 +  64) * 224 + cq, false)
        AW7(w28,w29,w30,w31,w32,w33,w34, W0h + (size_t)(s0 + 199) * 224 + cq, false)
        AW7(w35,w36,w37,w38,w39,w40,w41, W0h + (size_t)(s0 + 334) * 224 + cq, false)
        bA0 = b0c[s0];      bA1 = b0c[135 + s0]; bA2 = b0c[270 + s0];
        bB0 = b0c[64 + s0]; bB1 = b0c[199 + s0]; bB2 = b0c[334 + s0];
        vB = true;
    } else if (gL1) {
        const size_t cq = 56 * q;
        const bool vA = (s1 <= 44);
        vB = (s1 <= 43);
        const int ua = vA ? s1 : 0;
        const int ub = vB ? 45 + s1 : 0;
        AW7(w00,w01,w02,w03,w04,w05,w06, W1h + (size_t)(ua      ) * 224 + cq, !vA)
        AW7(w07,w08,w09,w10,w11,w12,w13, W1h + (size_t)(ua +  89) * 224 + cq, !vA)
        AW7(w14,w15,w16,w17,w18,w19,w20, W1h + (size_t)(ua + 178) * 224 + cq, !vA)
        AW7(w21,w22,w23,w24,w25,w26,w27, W1h + (size_t)(ub      ) * 224 + cq, !vB)
        AW7(w28,w29,w30,w31,w32,w33,w34, W1h + (size_t)(ub +  89) * 224 + cq, !vB)
        AW7(w35,w36,w37,w38,w39,w40,w41, W1h + (size_t)(ub + 178) * 224 + cq, !vB)
        if (vA) { bA0 = b1s[ua]; bA1 = b1s[89 + ua]; bA2 = b1s[178 + ua]; }
        if (vB) { bB0 = b1s[ub]; bB1 = b1s[89 + ub]; bB2 = b1s[178 + ub]; }
    } else {
        const size_t c2 = 32 * q;
        AW4B(w00,w01,w02,w03, W2h + (size_t)(s2     ) * 128 + c2)
        AW4B(w04,w05,w06,w07, W2h + (size_t)(s2 + 32) * 128 + c2)
        AW4B(w08,w09,w10,w11, W2h + (size_t)(s2 + 64) * 128 + c2)
        AW4B(w12,w13,w14,w15, W2h + (size_t)(s2 + 16) * 128 + c2)
        AW4B(w16,w17,w18,w19, W2h + (size_t)(s2 + 48) * 128 + c2)
        AW4B(w20,w21,w22,w23, W2h + (size_t)(s2 + 80) * 128 + c2)
        vX = (s2 < 7);
        if (vX) {   // stage leftover-L0 weights to LDS (per-lane chunk)
            const int ux = 128 + s2;
            const size_t cq = 56 * q;
            uint4* dst = &lwv[s2 * 4 + q][0];
            const uint4* p0 = (const uint4*)(W0h + (size_t)(ux      ) * 224 + cq);
            const uint4* p1 = (const uint4*)(W0h + (size_t)(ux + 135) * 224 + cq);
            const uint4* p2 = (const uint4*)(W0h + (size_t)(ux + 270) * 224 + cq);
#pragma unroll
            for (int j = 0; j < 7; ++j) { dst[j] = p0[j]; dst[7 + j] = p1[j]; dst[14 + j] = p2[j]; }
            bX0 = b0c[ux]; bX1 = b0c[135 + ux]; bX2 = b0c[270 + ux];
        }
        bA0 = b2s[s2];      bA1 = b2s[32 + s2]; bA2 = b2s[64 + s2];
        bB0 = b2s[16 + s2]; bB1 = b2s[48 + s2]; bB2 = b2s[80 + s2];
    }
    // keep biases resident (cheap pin)
    asm volatile("" : "+v"(bA0),"+v"(bA1),"+v"(bA2),"+v"(bB0),"+v"(bB1),"+v"(bB2),
                      "+v"(bX0),"+v"(bX1),"+v"(bX2));

    const float* xb = x + (size_t)b * TTs * DINn;
    float* cfb = cfc + (size_t)b * TTs * 32;

    __syncthreads();
    if (xi >= 0) ((half_t*)&z0v[0][0])[xi] = (half_t)xb[xi];   // x(0)
    __syncthreads();

#pragma unroll 1
    for (int k = 0; k < TTs + 2; ++k) {
        const int p = k & 1;
        half_t* z0n = (half_t*)&z0v[p ^ 1][0];
        half_t* z1n = (half_t*)&z1v[p ^ 1][0];
        half_t* z2n = (half_t*)&z2v[p ^ 1][0];

        if (gL0) {
            // ---- L0: h0^{k+1} over z0[p] ----
            const float4* zc = &z0v[p][q * 7];
            float4 f0 = zc[0], f1 = zc[1], f2 = zc[2], f3 = zc[3],
                   f4 = zc[4], f5 = zc[5], f6 = zc[6];
            float a0=0.f,a1=0.f,a2=0.f,a3=0.f,a4=0.f,a5=0.f;
            DR7A(a0, w00,w01,w02,w03,w04,w05,w06)
            DR7A(a1, w07,w08,w09,w10,w11,w12,w13)
            DR7A(a2, w14,w15,w16,w17,w18,w19,w20)
            DR7A(a3, w21,w22,w23,w24,w25,w26,w27)
            DR7A(a4, w28,w29,w30,w31,w32,w33,w34)
            DR7A(a5, w35,w36,w37,w38,w39,w40,w41)
            a0=qsum(a0); a1=qsum(a1); a2=qsum(a2);
            a3=qsum(a3); a4=qsum(a4); a5=qsum(a5);
            if (q == 0) {
                float h1v = cfc_comb(a0 + bA0, a1 + bA1, a2 + bA2);
                half_t hh1 = (half_t)h1v;
                z0n[64 + s0]  = hh1;
                z1n[s0]       = hh1;
                float h2v = cfc_comb(a3 + bB0, a4 + bB1, a5 + bB2);
                half_t hh2 = (half_t)h2v;
                z0n[128 + s0] = hh2;
                z1n[64 + s0]  = hh2;
            }
        } else if (gL1) {
            // ---- L1: h1^k over z1[p] ----
            const float4* zc = &z1v[p][q * 7];
            float4 f0 = zc[0], f1 = zc[1], f2 = zc[2], f3 = zc[3],
                   f4 = zc[4], f5 = zc[5], f6 = zc[6];
            float a0=0.f,a1=0.f,a2=0.f,a3=0.f,a4=0.f,a5=0.f;
            DR7A(a0, w00,w01,w02,w03,w04,w05,w06)
            DR7A(a1, w07,w08,w09,w10,w11,w12,w13)
            DR7A(a2, w14,w15,w16,w17,w18,w19,w20)
            DR7A(a3, w21,w22,w23,w24,w25,w26,w27)
            DR7A(a4, w28,w29,w30,w31,w32,w33,w34)
            DR7A(a5, w35,w36,w37,w38,w39,w40,w41)
            a0=qsum(a0); a1=qsum(a1); a2=qsum(a2);
            a3=qsum(a3); a4=qsum(a4); a5=qsum(a5);
            if (q == 0 && k >= 1) {
                if (s1 <= 44) {
                    float hv = cfc_comb(a0 + bA0, a1 + bA1, a2 + bA2);
                    half_t hh = (half_t)hv;
                    z1n[135 + s1] = hh;
                    z2n[s1]       = hh;
                }
                if (vB) {
                    float hv = cfc_comb(a3 + bB0, a4 + bB1, a5 + bB2);
                    half_t hh = (half_t)hv;
                    z1n[180 + s1] = hh;
                    z2n[45 + s1]  = hh;
                }
            }
        } else {
            // ---- wave 7: L2 h2^{k-1} + leftover L0 + x staging ----
            int tn = k + 1; if (tn > TTs - 1) tn = TTs - 1;
            float xnext = xb[(size_t)tn * DINn + xi];
            {
                const float4* zc = &z2v[p][q * 4];
                float4 f0 = zc[0], f1 = zc[1], f2 = zc[2], f3 = zc[3];
                float a0=0.f,a1=0.f,a2=0.f,a3=0.f,a4=0.f,a5=0.f;
                DR4A(a0, w00,w01,w02,w03)
                DR4A(a1, w04,w05,w06,w07)
                DR4A(a2, w08,w09,w10,w11)
                DR4A(a3, w12,w13,w14,w15)
                DR4A(a4, w16,w17,w18,w19)
                DR4A(a5, w20,w21,w22,w23)
                a0=qsum(a0); a1=qsum(a1); a2=qsum(a2);
                a3=qsum(a3); a4=qsum(a4); a5=qsum(a5);
                if (q == 0 && k >= 2) {
                    float hv0 = cfc_comb(a0 + bA0, a1 + bA1, a2 + bA2);
                    z2n[89 + s2]  = (half_t)hv0;
                    cfb[(size_t)(k - 2) * 32 + s2] = hv0;
                    float hv1 = cfc_comb(a3 + bB0, a4 + bB1, a5 + bB2);
                    z2n[105 + s2] = (half_t)hv1;
                    cfb[(size_t)(k - 2) * 32 + 16 + s2] = hv1;
                }
            }
            if (vX) {   // leftover L0 units 128..134, weights from LDS
                const float4* zc = &z0v[p][q * 7];
                float4 f0 = zc[0], f1 = zc[1], f2 = zc[2], f3 = zc[3],
                       f4 = zc[4], f5 = zc[5], f6 = zc[6];
                const uint4* lwp = &lwv[s2 * 4 + q][0];
                float c0=0.f,c1=0.f,c2=0.f;
                { uint4 _t=lwp[0];  D4(c0,_t,f0) } { uint4 _t=lwp[1];  D4(c0,_t,f1) }
                { uint4 _t=lwp[2];  D4(c0,_t,f2) } { uint4 _t=lwp[3];  D4(c0,_t,f3) }
                { uint4 _t=lwp[4];  D4(c0,_t,f4) } { uint4 _t=lwp[5];  D4(c0,_t,f5) }
                { uint4 _t=lwp[6];  D4(c0,_t,f6) }
                { uint4 _t=lwp[7];  D4(c1,_t,f0) } { uint4 _t=lwp[8];  D4(c1,_t,f1) }
                { uint4 _t=lwp[9];  D4(c1,_t,f2) } { uint4 _t=lwp[10]; D4(c1,_t,f3) }
                { uint4 _t=lwp[11]; D4(c1,_t,f4) } { uint4 _t=lwp[12]; D4(c1,_t,f5) }
                { uint4 _t=lwp[13]; D4(c1,_t,f6) }
                { uint4 _t=lwp[14]; D4(c2,_t,f0) } { uint4 _t=lwp[15]; D4(c2,_t,f1) }
                { uint4 _t=lwp[16]; D4(c2,_t,f2) } { uint4 _t=lwp[17]; D4(c2,_t,f3) }
                { uint4 _t=lwp[18]; D4(c2,_t,f4) } { uint4 _t=lwp[19]; D4(c2,_t,f5) }
                { uint4 _t=lwp[20]; D4(c2,_t,f6) }
                c0=qsum(c0); c1=qsum(c1); c2=qsum(c2);
                if (q == 0) {
                    float hv = cfc_comb(c0 + bX0, c1 + bX1, c2 + bX2);
                    half_t hh = (half_t)hv;
                    z0n[192 + s2] = hh;
                    z1n[128 + s2] = hh;
                }
            }
            z0n[xi] = (half_t)xnext;   // x(k+1)
        }
        BAR();
    }
}

// ---------------- head: in-place gelu(cfc@Wh1.T+bh1)@Wh2.T + bh2 ----------------
__global__ __launch_bounds__(256) void k_head(float* io,
                                              const float* __restrict__ Wh1,
                                              const float* __restrict__ bh1,
                                              const float* __restrict__ Wh2T,
                                              const float* __restrict__ bh2)
{
    const int bt = blockIdx.x * 256 + threadIdx.x;
    float c32[32];
    const float4* cp = (const float4*)(io + (size_t)bt * 32);
#pragma unroll
    for (int k = 0; k < 8; ++k) {
        float4 v = cp[k];
        c32[4 * k] = v.x; c32[4 * k + 1] = v.y; c32[4 * k + 2] = v.z; c32[4 * k + 3] = v.w;
    }
    float acc[32];
#pragma unroll
    for (int o = 0; o < 32; ++o) acc[o] = bh2[o];
#pragma unroll 1
    for (int h = 0; h < HPn; ++h) {
        float ss = bh1[h];
        const float* w1r = Wh1 + (size_t)h * 32;
#pragma unroll
        for (int k = 0; k < 32; ++k) ss += c32[k] * w1r[k];
        float g = 0.5f * ss * (1.f + erff(ss * 0.70710678118654752440f));
        const float* w2r = Wh2T + (size_t)h * 32;
#pragma unroll
        for (int o = 0; o < 32; ++o) acc[o] += g * w2r[o];
    }
    float4* op = (float4*)(io + (size_t)bt * 32);
#pragma unroll
    for (int k = 0; k < 8; ++k) {
        float4 v;
        v.x = acc[4 * k]; v.y = acc[4 * k + 1]; v.z = acc[4 * k + 2]; v.w = acc[4 * k + 3];
        op[k] = v;
    }
}

// ---------------- launch ----------------
extern "C" void kernel_launch(void* const* d_in, const int* in_sizes, int n_in,
                              void* d_out, int out_size, void* d_ws, size_t ws_size,
                              hipStream_t stream)
{
    (void)in_sizes; (void)n_in; (void)out_size; (void)ws_size;
    const float* x      = (const float*)d_in[0];
    const float* Wp     = (const float*)d_in[1];
    const float* bp     = (const float*)d_in[2];
    const float* Wff1_0 = (const float*)d_in[3];
    const float* bff1_0 = (const float*)d_in[4];
    const float* Wff2_0 = (const float*)d_in[5];
    const float* bff2_0 = (const float*)d_in[6];
    const float* Wta_0  = (const float*)d_in[7];
    const float* bta_0  = (const float*)d_in[8];
    const float* Wtb_0  = (const float*)d_in[9];
    const float* btb_0  = (const float*)d_in[10];
    const unsigned char* mask_0 = (const unsigned char*)d_in[11];
    const float* Wff1_1 = (const float*)d_in[12];
    const float* bff1_1 = (const float*)d_in[13];
    const float* Wff2_1 = (const float*)d_in[14];
    const float* bff2_1 = (const float*)d_in[15];
    const float* Wta_1  = (const float*)d_in[16];
    const float* bta_1  = (const float*)d_in[17];
    const float* Wtb_1  = (const float*)d_in[18];
    const float* btb_1  = (const float*)d_in[19];
    const unsigned char* mask_1 = (const unsigned char*)d_in[20];
    const float* Wff1_2 = (const float*)d_in[21];
    const float* bff1_2 = (const float*)d_in[22];
    const float* Wff2_2 = (const float*)d_in[23];
    const float* bff2_2 = (const float*)d_in[24];
    const float* Wta_2  = (const float*)d_in[25];
    const float* bta_2  = (const float*)d_in[26];
    const float* Wtb_2  = (const float*)d_in[27];
    const float* btb_2  = (const float*)d_in[28];
    const unsigned char* mask_2 = (const unsigned char*)d_in[29];
    const float* Wh1    = (const float*)d_in[30];
    const float* bh1    = (const float*)d_in[31];
    const float* Wh2    = (const float*)d_in[32];
    const float* bh2    = (const float*)d_in[33];

    float* ws = (float*)d_ws;
    size_t o = 0;
    float* Wh0s = ws + o; o += (size_t)R0c * U0c;
    float* Wx0s = ws + o; o += (size_t)R0c * HPn;
    float* b0s  = ws + o; o += R0c; o += 3;
    float* Wcb  = ws + o; o += (size_t)R0c * DINn;
    float* b0c  = ws + o; o += R0c; o += 3;
    float* W1s  = ws + o; o += (size_t)R1c * C1c;
    float* b1s  = ws + o; o += R1c; o += 1;
    float* W2s  = ws + o; o += (size_t)R2c * C2c;
    float* b2s  = ws + o; o += R2c;
    float* Wh2T = ws + o; o += (size_t)HPn * 32;
    half_t* W0h = (half_t*)(ws + o); o += (size_t)R0c * 224 / 2;
    half_t* W1h = (half_t*)(ws + o); o += (size_t)R1c * 224 / 2;
    half_t* W2h = (half_t*)(ws + o); o += (size_t)R2c * 128 / 2;

    k_stack<<<128, 256, 0, stream>>>(Wff1_0, bff1_0, Wff2_0, bff2_0, Wta_0, bta_0, Wtb_0, btb_0,
                                     mask_0, U0c, C0c, HPn, Wx0s, Wh0s, b0s);
    k_stack<<<64, 256, 0, stream>>>(Wff1_1, bff1_1, Wff2_1, bff2_1, Wta_1, bta_1, Wtb_1, btb_1,
                                    mask_1, U1c, C1c, C1c, W1s, W1s, b1s);
    k_stack<<<16, 256, 0, stream>>>(Wff1_2, bff1_2, Wff2_2, bff2_2, Wta_2, bta_2, Wtb_2, btb_2,
                                    mask_2, U2c, C2c, C2c, W2s, W2s, b2s);
    k_comb<<<R0c, DINn, 0, stream>>>(Wx0s, Wp, Wcb);
    k_biasc<<<32, 256, 0, stream>>>(Wx0s, bp, b0s, b0c, Wh2, Wh2T);
    k_pack<<<320, 256, 0, stream>>>(Wcb, Wh0s, W1s, W2s, W0h, W1h, W2h);
    k_scan<<<BBn, 512, 0, stream>>>(W0h, W1h, W2h, b0c, b1s, b2s, x, (float*)d_out);
    k_head<<<(int)(BTn / 256), 256, 0, stream>>>((float*)d_out, Wh1, bh1, Wh2T, bh2);
}

// Round 10
// 3335.799 us; speedup vs baseline: 1.3970x; 1.3970x over previous
//
#include <hip/hip_runtime.h>
#include <cstdint>
#include <cstddef>

typedef _Float16 half_t;
typedef half_t half2_t __attribute__((ext_vector_type(2)));

static constexpr int TTs = 2048;   // timesteps
static constexpr int BBn = 64;     // batch
static constexpr int DINn = 64;    // input dim
static constexpr int HPn  = 256;   // proj dim
static constexpr int U0c = 135, C0c = 391, R0c = 405;   // layer0
static constexpr int U1c = 89,  C1c = 224, R1c = 267;   // layer1
static constexpr int U2c = 32,  C2c = 121, R2c = 96;    // layer2
static constexpr size_t BTn = (size_t)BBn * TTs;        // 131072

// ---------------- math helpers ----------------
__device__ __forceinline__ float tanh_f(float x) {
    return 1.f - __fdividef(2.f, __expf(2.f * x) + 1.f);
}
__device__ __forceinline__ float sigm_f(float x) {
    return __fdividef(1.f, 1.f + __expf(-x));
}
__device__ __forceinline__ float cfc_comb(float y0, float y1, float y2) {
    float f1 = tanh_f(y0), f2 = tanh_f(y1), ti = sigm_f(y2);
    return f1 + ti * (f2 - f1);
}
// quad butterfly sum via DPP (VALU pipe, no LDS)
__device__ __forceinline__ float qsum(float v) {
    v += __builtin_bit_cast(float, __builtin_amdgcn_update_dpp(
             0, __builtin_bit_cast(int, v), 0xB1, 0xF, 0xF, true));  // [1,0,3,2]
    v += __builtin_bit_cast(float, __builtin_amdgcn_update_dpp(
             0, __builtin_bit_cast(int, v), 0x4E, 0xF, 0xF, true));  // [2,3,0,1]
    return v;
}
__device__ __forceinline__ half2_t h2(unsigned u) { return __builtin_bit_cast(half2_t, u); }

// ---------------- mask dtype probe ----------------
__device__ __forceinline__ int mask_mode(const unsigned char* mp) {
    const unsigned* wp = (const unsigned*)mp;
    bool all01 = true, allf = true;
    for (int k = 0; k < 64; ++k) {
        unsigned w = wp[k];
        all01 = all01 && (w == 0u || w == 1u);
        allf  = allf  && (w == 0u || w == 0x3F800000u);
    }
    if (all01) return 0;
    if (allf)  return 1;
    return 2;
}
__device__ __forceinline__ bool mget(const unsigned char* mp, int mode, int idx) {
    if (mode == 0) return ((const int*)mp)[idx] != 0;
    if (mode == 1) return ((const float*)mp)[idx] != 0.f;
    return mp[idx] != 0;
}

// ---------------- prep: stack + mask weights ----------------
__global__ void k_stack(const float* __restrict__ Wff1, const float* __restrict__ bff1,
                        const float* __restrict__ Wff2, const float* __restrict__ bff2,
                        const float* __restrict__ Wta,  const float* __restrict__ bta,
                        const float* __restrict__ Wtb,  const float* __restrict__ btb,
                        const unsigned char* __restrict__ maskraw,
                        int u, int c, int split,
                        float* __restrict__ outA, float* __restrict__ outB,
                        float* __restrict__ bias_out)
{
    const int mode = mask_mode(maskraw);
    const int total = 3 * u * c + 3 * u;
    for (int idx = blockIdx.x * blockDim.x + threadIdx.x; idx < total;
         idx += gridDim.x * blockDim.x) {
        if (idx < 3 * u * c) {
            int m = idx / (u * c);
            int rem = idx - m * u * c;
            int r = rem / c;
            int k = rem - r * c;
            float v;
            if (m == 2) {
                v = Wta[r * c + k] + Wtb[r * c + k];
            } else {
                bool mk = mget(maskraw, mode, r * c + k);
                float w = (m == 0) ? Wff1[r * c + k] : Wff2[r * c + k];
                v = mk ? w : 0.f;
            }
            int R = m * u + r;
            if (k < split) outA[(size_t)R * split + k] = v;
            else           outB[(size_t)R * (c - split) + (k - split)] = v;
        } else {
            int j = idx - 3 * u * c;
            int m = j / u, r = j - m * u;
            bias_out[j] = (m == 0) ? bff1[r] : ((m == 1) ? bff2[r] : (bta[r] + btb[r]));
        }
    }
}

// ---------------- prep: Wcomb = Wx0s (405x256) @ Wp (256x64) ----------------
__global__ void k_comb(const float* __restrict__ Wx0s, const float* __restrict__ Wp,
                       float* __restrict__ Wcomb)
{
    const int r = blockIdx.x;
    const int d = threadIdx.x;
    float acc = 0.f;
    for (int k = 0; k < HPn; ++k) acc += Wx0s[(size_t)r * HPn + k] * Wp[(size_t)k * DINn + d];
    Wcomb[(size_t)r * DINn + d] = acc;
}

// ---------------- prep: folded bias + Wh2 transpose ----------------
__global__ void k_biasc(const float* __restrict__ Wx0s, const float* __restrict__ bp,
                        const float* __restrict__ b0, float* __restrict__ b0c,
                        const float* __restrict__ Wh2, float* __restrict__ Wh2T)
{
    const int i = blockIdx.x * blockDim.x + threadIdx.x;
    if (i < R0c) {
        float a = b0[i];
        for (int k = 0; k < HPn; ++k) a += Wx0s[(size_t)i * HPn + k] * bp[k];
        b0c[i] = a;
    }
    if (i < HPn * 32) {
        int h = i >> 5, o = i & 31;
        Wh2T[i] = Wh2[(size_t)o * HPn + h];
    }
}

// ---------------- prep: pack weights to padded fp16 ----------------
// W0h (405,224): [Wcb:64 | Wh0s:135 | 0:25]; W1h (267,224); W2h (96,128): [W2s:121|0:7]
__global__ void k_pack(const float* __restrict__ Wcb, const float* __restrict__ Wh0s,
                       const float* __restrict__ W1s, const float* __restrict__ W2s,
                       half_t* __restrict__ W0h, half_t* __restrict__ W1h,
                       half_t* __restrict__ W2h)
{
    const int N0 = R0c * 224, N1 = R1c * 224, N2 = R2c * 128;
    for (int idx = blockIdx.x * blockDim.x + threadIdx.x; idx < N0 + N1 + N2;
         idx += gridDim.x * blockDim.x) {
        if (idx < N0) {
            int r = idx / 224, c = idx - r * 224;
            float v = (c < 64) ? Wcb[(size_t)r * 64 + c]
                               : ((c < 199) ? Wh0s[(size_t)r * 135 + (c - 64)] : 0.f);
            W0h[idx] = (half_t)v;
        } else if (idx < N0 + N1) {
            int i = idx - N0;
            W1h[i] = (half_t)W1s[i];
        } else {
            int i = idx - N0 - N1;
            int r = i / 128, c = i - r * 128;
            W2h[i] = (half_t)((c < 121) ? W2s[(size_t)r * 121 + c] : 0.f);
        }
    }
}

// ---------------- prep: x fp32 -> fp16 (halves the streamed bytes; L3-resident) --
__global__ __launch_bounds__(256) void k_xh(const float* __restrict__ x,
                                            half_t* __restrict__ xh)
{
    size_t i = ((size_t)blockIdx.x * 256 + threadIdx.x) * 4;
    if (i >= BTn * (size_t)DINn) return;
    float4 v = *(const float4*)(x + i);
    half_t* o = xh + i;
    o[0] = (half_t)v.x; o[1] = (half_t)v.y; o[2] = (half_t)v.z; o[3] = (half_t)v.w;
}

// light barrier: LDS-ordering only; vmem stays in flight.
#define BAR() asm volatile("s_waitcnt lgkmcnt(0)\n\ts_barrier" ::: "memory")

#define LD7(a,b,c,d,e,f,g, ptr) { const uint4* _p = (const uint4*)(ptr); \
    a=_p[0]; b=_p[1]; c=_p[2]; d=_p[3]; e=_p[4]; f=_p[5]; g=_p[6]; }
#define LD4(a,b,c,d, ptr) { const uint4* _p = (const uint4*)(ptr); \
    a=_p[0]; b=_p[1]; c=_p[2]; d=_p[3]; }
#define Z7(a,b,c,d,e,f,g) a=z4u; b=z4u; c=z4u; d=z4u; e=z4u; f=z4u; g=z4u;
#define D4(acc, W, F) \
    acc = __builtin_amdgcn_fdot2(h2((W).x), __builtin_bit_cast(half2_t,(F).x), acc, false); \
    acc = __builtin_amdgcn_fdot2(h2((W).y), __builtin_bit_cast(half2_t,(F).y), acc, false); \
    acc = __builtin_amdgcn_fdot2(h2((W).z), __builtin_bit_cast(half2_t,(F).z), acc, false); \
    acc = __builtin_amdgcn_fdot2(h2((W).w), __builtin_bit_cast(half2_t,(F).w), acc, false);
#define DR7(acc, A,B,C,D,E,F,G) D4(acc,A,f0) D4(acc,B,f1) D4(acc,C,f2) \
    D4(acc,D,f3) D4(acc,E,f4) D4(acc,F,f5) D4(acc,G,f6)
#define DR4(acc, A,B,C,D) D4(acc,A,f0) D4(acc,B,f1) D4(acc,C,f2) D4(acc,D,f3)

// ---------------- pipelined recurrent scan: 64 blocks x 512 threads ----------
// Round-8 structure (verified, 3025 us): iteration k runs L0 | L1 | L2 skewed,
// one light barrier per iteration, double-buffered state. Round-10 change:
// x is streamed as fp16 (if workspace allows) and DOUBLE-prefetched -- the
// load issued at iter k targets step k+2, so it has a full iteration of
// latency budget instead of stalling wave 7 (and thus the barrier)每 step.
__global__ __launch_bounds__(512) void k_scan(
    const half_t* __restrict__ W0h,   // (405,224)
    const half_t* __restrict__ W1h,   // (267,224)
    const half_t* __restrict__ W2h,   // (96,128)
    const float* __restrict__ b0c,    // (405)
    const float* __restrict__ b1s,    // (267)
    const float* __restrict__ b2s,    // (96)
    const float* __restrict__ x,      // (B,T,64) fp32
    const half_t* __restrict__ xh,    // (B,T,64) fp16 (may be null)
    int use_xh,
    float* __restrict__ cfc)          // (B,T,32)
{
    const int t = threadIdx.x;
    const int b = blockIdx.x;
    const int q = t & 3;

    __shared__ float4 z0v[2][28];   // 224 halfs: [x:64 | h0:135 | 0:25]
    __shared__ float4 z1v[2][28];   // 224 halfs: [h0:135 | h1:89]
    __shared__ float4 z2v[2][16];   // 128 halfs: [h1:89 | h2:32 | 0:7]

    {
        float4* zz = (float4*)z0v;
        for (int i = t; i < 144; i += 512) zz[i] = make_float4(0.f, 0.f, 0.f, 0.f);
    }

    const bool gL0 = (t < 256);
    const bool gL1 = (t >= 256) && (t < 448);
    const int s0 = t >> 2;            // 0..63   (L0)
    const int s1 = (t - 256) >> 2;    // 0..47   (L1)
    const int s2 = (t - 448) >> 2;    // 0..15   (L2)
    const int xi = t - 448;           // wave 7 stages x

    // ---- shared weight set: 45 named uint4 ----
    const uint4 z4u = make_uint4(0u, 0u, 0u, 0u);
    uint4 w00,w01,w02,w03,w04,w05,w06, w07,w08,w09,w10,w11,w12,w13;
    uint4 w14,w15,w16,w17,w18,w19,w20, w21,w22,w23,w24,w25,w26,w27;
    uint4 w28,w29,w30,w31,w32,w33,w34, w35,w36,w37,w38,w39,w40,w41;
    uint4 w42,w43,w44;
    Z7(w00,w01,w02,w03,w04,w05,w06) Z7(w07,w08,w09,w10,w11,w12,w13)
    Z7(w14,w15,w16,w17,w18,w19,w20) Z7(w21,w22,w23,w24,w25,w26,w27)
    Z7(w28,w29,w30,w31,w32,w33,w34) Z7(w35,w36,w37,w38,w39,w40,w41)
    w42 = z4u; w43 = z4u; w44 = z4u;

    float bA0=0.f,bA1=0.f,bA2=0.f, bB0=0.f,bB1=0.f,bB2=0.f, bX0=0.f,bX1=0.f,bX2=0.f;
    bool vB = false, vX = false;

    if (gL0) {
        const size_t cq = 56 * q;
        LD7(w00,w01,w02,w03,w04,w05,w06, W0h + (size_t)(s0      ) * 224 + cq)
        LD7(w07,w08,w09,w10,w11,w12,w13, W0h + (size_t)(s0 + 135) * 224 + cq)
        LD7(w14,w15,w16,w17,w18,w19,w20, W0h + (size_t)(s0 + 270) * 224 + cq)
        LD7(w21,w22,w23,w24,w25,w26,w27, W0h + (size_t)(s0 +  64) * 224 + cq)
        LD7(w28,w29,w30,w31,w32,w33,w34, W0h + (size_t)(s0 + 199) * 224 + cq)
        LD7(w35,w36,w37,w38,w39,w40,w41, W0h + (size_t)(s0 + 334) * 224 + cq)
        bA0 = b0c[s0];      bA1 = b0c[135 + s0]; bA2 = b0c[270 + s0];
        bB0 = b0c[64 + s0]; bB1 = b0c[199 + s0]; bB2 = b0c[334 + s0];
        vB = true;
    } else if (gL1) {
        const size_t cq = 56 * q;
        const bool vA = (s1 <= 44);
        vB = (s1 <= 43);
        const int ua = vA ? s1 : 0;
        const int ub = vB ? 45 + s1 : 0;
        LD7(w00,w01,w02,w03,w04,w05,w06, W1h + (size_t)(ua      ) * 224 + cq)
        LD7(w07,w08,w09,w10,w11,w12,w13, W1h + (size_t)(ua +  89) * 224 + cq)
        LD7(w14,w15,w16,w17,w18,w19,w20, W1h + (size_t)(ua + 178) * 224 + cq)
        LD7(w21,w22,w23,w24,w25,w26,w27, W1h + (size_t)(ub      ) * 224 + cq)
        LD7(w28,w29,w30,w31,w32,w33,w34, W1h + (size_t)(ub +  89) * 224 + cq)
        LD7(w35,w36,w37,w38,w39,w40,w41, W1h + (size_t)(ub + 178) * 224 + cq)
        if (!vA) { Z7(w00,w01,w02,w03,w04,w05,w06) Z7(w07,w08,w09,w10,w11,w12,w13)
                   Z7(w14,w15,w16,w17,w18,w19,w20) }
        if (!vB) { Z7(w21,w22,w23,w24,w25,w26,w27) Z7(w28,w29,w30,w31,w32,w33,w34)
                   Z7(w35,w36,w37,w38,w39,w40,w41) }
        if (vA) { bA0 = b1s[ua]; bA1 = b1s[89 + ua]; bA2 = b1s[178 + ua]; }
        if (vB) { bB0 = b1s[ub]; bB1 = b1s[89 + ub]; bB2 = b1s[178 + ub]; }
    } else {
        const size_t c2 = 32 * q;
        LD4(w00,w01,w02,w03, W2h + (size_t)(s2     ) * 128 + c2)
        LD4(w04,w05,w06,w07, W2h + (size_t)(s2 + 32) * 128 + c2)
        LD4(w08,w09,w10,w11, W2h + (size_t)(s2 + 64) * 128 + c2)
        LD4(w12,w13,w14,w15, W2h + (size_t)(s2 + 16) * 128 + c2)
        LD4(w16,w17,w18,w19, W2h + (size_t)(s2 + 48) * 128 + c2)
        LD4(w20,w21,w22,w23, W2h + (size_t)(s2 + 80) * 128 + c2)
        vX = (s2 < 7);
        const int ux = vX ? 128 + s2 : 128;
        const size_t cq = 56 * q;
        LD7(w24,w25,w26,w27,w28,w29,w30, W0h + (size_t)(ux      ) * 224 + cq)
        LD7(w31,w32,w33,w34,w35,w36,w37, W0h + (size_t)(ux + 135) * 224 + cq)
        LD7(w38,w39,w40,w41,w42,w43,w44, W0h + (size_t)(ux + 270) * 224 + cq)
        if (!vX) { Z7(w24,w25,w26,w27,w28,w29,w30) Z7(w31,w32,w33,w34,w35,w36,w37)
                   Z7(w38,w39,w40,w41,w42,w43,w44) }
        bA0 = b2s[s2];      bA1 = b2s[32 + s2]; bA2 = b2s[64 + s2];
        bB0 = b2s[16 + s2]; bB1 = b2s[48 + s2]; bB2 = b2s[80 + s2];
        if (vX) { bX0 = b0c[ux]; bX1 = b0c[135 + ux]; bX2 = b0c[270 + ux]; }
    }

    const float*  xb  = x  + (size_t)b * TTs * DINn;
    const half_t* xbh = xh + (size_t)b * TTs * DINn;   // valid only if use_xh
    float* cfb = cfc + (size_t)b * TTs * 32;

    __syncthreads();
    half_t xr = (half_t)0.f;   // holds x(k+1) at entry of iter k (wave 7)
    if (xi >= 0) {
        ((half_t*)&z0v[0][0])[xi] = use_xh ? xbh[xi] : (half_t)xb[xi];       // x(0)
        xr = use_xh ? xbh[DINn + xi] : (half_t)xb[DINn + xi];                // x(1)
    }
    __syncthreads();

#pragma unroll 1
    for (int k = 0; k < TTs + 2; ++k) {
        const int p = k & 1;
        half_t* z0n = (half_t*)&z0v[p ^ 1][0];
        half_t* z1n = (half_t*)&z1v[p ^ 1][0];
        half_t* z2n = (half_t*)&z2v[p ^ 1][0];

        if (gL0) {
            // ---- L0: h0^{k+1} over z0[p] ----
            const float4* zc = &z0v[p][q * 7];
            float4 f0 = zc[0], f1 = zc[1], f2 = zc[2], f3 = zc[3],
                   f4 = zc[4], f5 = zc[5], f6 = zc[6];
            float a0=0.f,a1=0.f,a2=0.f,a3=0.f,a4=0.f,a5=0.f;
            DR7(a0, w00,w01,w02,w03,w04,w05,w06)
            DR7(a1, w07,w08,w09,w10,w11,w12,w13)
            DR7(a2, w14,w15,w16,w17,w18,w19,w20)
            DR7(a3, w21,w22,w23,w24,w25,w26,w27)
            DR7(a4, w28,w29,w30,w31,w32,w33,w34)
            DR7(a5, w35,w36,w37,w38,w39,w40,w41)
            a0=qsum(a0); a1=qsum(a1); a2=qsum(a2);
            a3=qsum(a3); a4=qsum(a4); a5=qsum(a5);
            if (q == 0) {
                float h1v = cfc_comb(a0 + bA0, a1 + bA1, a2 + bA2);
                half_t hh1 = (half_t)h1v;
                z0n[64 + s0]  = hh1;
                z1n[s0]       = hh1;
                float h2v = cfc_comb(a3 + bB0, a4 + bB1, a5 + bB2);
                half_t hh2 = (half_t)h2v;
                z0n[128 + s0] = hh2;
                z1n[64 + s0]  = hh2;
            }
        } else if (gL1) {
            // ---- L1: h1^k over z1[p] ----
            const float4* zc = &z1v[p][q * 7];
            float4 f0 = zc[0], f1 = zc[1], f2 = zc[2], f3 = zc[3],
                   f4 = zc[4], f5 = zc[5], f6 = zc[6];
            float a0=0.f,a1=0.f,a2=0.f,a3=0.f,a4=0.f,a5=0.f;
            DR7(a0, w00,w01,w02,w03,w04,w05,w06)
            DR7(a1, w07,w08,w09,w10,w11,w12,w13)
            DR7(a2, w14,w15,w16,w17,w18,w19,w20)
            DR7(a3, w21,w22,w23,w24,w25,w26,w27)
            DR7(a4, w28,w29,w30,w31,w32,w33,w34)
            DR7(a5, w35,w36,w37,w38,w39,w40,w41)
            a0=qsum(a0); a1=qsum(a1); a2=qsum(a2);
            a3=qsum(a3); a4=qsum(a4); a5=qsum(a5);
            if (q == 0 && k >= 1) {
                if (s1 <= 44) {
                    float hv = cfc_comb(a0 + bA0, a1 + bA1, a2 + bA2);
                    half_t hh = (half_t)hv;
                    z1n[135 + s1] = hh;
                    z2n[s1]       = hh;
                }
                if (vB) {
                    float hv = cfc_comb(a3 + bB0, a4 + bB1, a5 + bB2);
                    half_t hh = (half_t)hv;
                    z1n[180 + s1] = hh;
                    z2n[45 + s1]  = hh;
                }
            }
        } else {
            // ---- wave 7: L2 h2^{k-1} + leftover L0 + x staging ----
            {
                const float4* zc = &z2v[p][q * 4];
                float4 f0 = zc[0], f1 = zc[1], f2 = zc[2], f3 = zc[3];
                float a0=0.f,a1=0.f,a2=0.f,a3=0.f,a4=0.f,a5=0.f;
                DR4(a0, w00,w01,w02,w03)
                DR4(a1, w04,w05,w06,w07)
                DR4(a2, w08,w09,w10,w11)
                DR4(a3, w12,w13,w14,w15)
                DR4(a4, w16,w17,w18,w19)
                DR4(a5, w20,w21,w22,w23)
                a0=qsum(a0); a1=qsum(a1); a2=qsum(a2);
                a3=qsum(a3); a4=qsum(a4); a5=qsum(a5);
                if (q == 0 && k >= 2) {
                    float hv0 = cfc_comb(a0 + bA0, a1 + bA1, a2 + bA2);
                    z2n[89 + s2]  = (half_t)hv0;
                    cfb[(size_t)(k - 2) * 32 + s2] = hv0;
                    float hv1 = cfc_comb(a3 + bB0, a4 + bB1, a5 + bB2);
                    z2n[105 + s2] = (half_t)hv1;
                    cfb[(size_t)(k - 2) * 32 + 16 + s2] = hv1;
                }
            }
            if (vX) {   // leftover L0 units 128..134
                const float4* zc = &z0v[p][q * 7];
                float4 f0 = zc[0], f1 = zc[1], f2 = zc[2], f3 = zc[3],
                       f4 = zc[4], f5 = zc[5], f6 = zc[6];
                float c0=0.f,c1=0.f,c2=0.f;
                DR7(c0, w24,w25,w26,w27,w28,w29,w30)
                DR7(c1, w31,w32,w33,w34,w35,w36,w37)
                DR7(c2, w38,w39,w40,w41,w42,w43,w44)
                c0=qsum(c0); c1=qsum(c1); c2=qsum(c2);
                if (q == 0) {
                    float hv = cfc_comb(c0 + bX0, c1 + bX1, c2 + bX2);
                    half_t hh = (half_t)hv;
                    z0n[192 + s2] = hh;
                    z1n[128 + s2] = hh;
                }
            }
            // x staging: write x(k+1) (loaded last iter), issue load of x(k+2)
            z0n[xi] = xr;
            int tn = k + 2; if (tn > TTs - 1) tn = TTs - 1;
            xr = use_xh ? xbh[(size_t)tn * DINn + xi]
                        : (half_t)xb[(size_t)tn * DINn + xi];
        }
        BAR();
    }
}

// ---------------- head: in-place gelu(cfc@Wh1.T+bh1)@Wh2.T + bh2 ----------------
__global__ __launch_bounds__(256) void k_head(float* io,
                                              const float* __restrict__ Wh1,
                                              const float* __restrict__ bh1,
                                              const float* __restrict__ Wh2T,
                                              const float* __restrict__ bh2)
{
    const int bt = blockIdx.x * 256 + threadIdx.x;
    float c32[32];
    const float4* cp = (const float4*)(io + (size_t)bt * 32);
#pragma unroll
    for (int k = 0; k < 8; ++k) {
        float4 v = cp[k];
        c32[4 * k] = v.x; c32[4 * k + 1] = v.y; c32[4 * k + 2] = v.z; c32[4 * k + 3] = v.w;
    }
    float acc[32];
#pragma unroll
    for (int o = 0; o < 32; ++o) acc[o] = bh2[o];
#pragma unroll 1
    for (int h = 0; h < HPn; ++h) {
        float ss = bh1[h];
        const float* w1r = Wh1 + (size_t)h * 32;
#pragma unroll
        for (int k = 0; k < 32; ++k) ss += c32[k] * w1r[k];
        float g = 0.5f * ss * (1.f + erff(ss * 0.70710678118654752440f));
        const float* w2r = Wh2T + (size_t)h * 32;
#pragma unroll
        for (int o = 0; o < 32; ++o) acc[o] += g * w2r[o];
    }
    float4* op = (float4*)(io + (size_t)bt * 32);
#pragma unroll
    for (int k = 0; k < 8; ++k) {
        float4 v;
        v.x = acc[4 * k]; v.y = acc[4 * k + 1]; v.z = acc[4 * k + 2]; v.w = acc[4 * k + 3];
        op[k] = v;
    }
}

// ---------------- launch ----------------
extern "C" void kernel_launch(void* const* d_in, const int* in_sizes, int n_in,
                              void* d_out, int out_size, void* d_ws, size_t ws_size,
                              hipStream_t stream)
{
    (void)in_sizes; (void)n_in; (void)out_size;
    const float* x      = (const float*)d_in[0];
    const float* Wp     = (const float*)d_in[1];
    const float* bp     = (const float*)d_in[2];
    const float* Wff1_0 = (const float*)d_in[3];
    const float* bff1_0 = (const float*)d_in[4];
    const float* Wff2_0 = (const float*)d_in[5];
    const float* bff2_0 = (const float*)d_in[6];
    const float* Wta_0  = (const float*)d_in[7];
    const float* bta_0  = (const float*)d_in[8];
    const float* Wtb_0  = (const float*)d_in[9];
    const float* btb_0  = (const float*)d_in[10];
    const unsigned char* mask_0 = (const unsigned char*)d_in[11];
    const float* Wff1_1 = (const float*)d_in[12];
    const float* bff1_1 = (const float*)d_in[13];
    const float* Wff2_1 = (const float*)d_in[14];
    const float* bff2_1 = (const float*)d_in[15];
    const float* Wta_1  = (const float*)d_in[16];
    const float* bta_1  = (const float*)d_in[17];
    const float* Wtb_1  = (const float*)d_in[18];
    const float* btb_1  = (const float*)d_in[19];
    const unsigned char* mask_1 = (const unsigned char*)d_in[20];
    const float* Wff1_2 = (const float*)d_in[21];
    const float* bff1_2 = (const float*)d_in[22];
    const float* Wff2_2 = (const float*)d_in[23];
    const float* bff2_2 = (const float*)d_in[24];
    const float* Wta_2  = (const float*)d_in[25];
    const float* bta_2  = (const float*)d_in[26];
    const float* Wtb_2  = (const float*)d_in[27];
    const float* btb_2  = (const float*)d_in[28];
    const unsigned char* mask_2 = (const unsigned char*)d_in[29];
    const float* Wh1    = (const float*)d_in[30];
    const float* bh1    = (const float*)d_in[31];
    const float* Wh2    = (const float*)d_in[32];
    const float* bh2    = (const float*)d_in[33];

    float* ws = (float*)d_ws;
    size_t o = 0;
    float* Wh0s = ws + o; o += (size_t)R0c * U0c;
    float* Wx0s = ws + o; o += (size_t)R0c * HPn;
    float* b0s  = ws + o; o += R0c; o += 3;
    float* Wcb  = ws + o; o += (size_t)R0c * DINn;
    float* b0c  = ws + o; o += R0c; o += 3;
    float* W1s  = ws + o; o += (size_t)R1c * C1c;
    float* b1s  = ws + o; o += R1c; o += 1;
    float* W2s  = ws + o; o += (size_t)R2c * C2c;
    float* b2s  = ws + o; o += R2c;
    float* Wh2T = ws + o; o += (size_t)HPn * 32;
    half_t* W0h = (half_t*)(ws + o); o += (size_t)R0c * 224 / 2;
    half_t* W1h = (half_t*)(ws + o); o += (size_t)R1c * 224 / 2;
    half_t* W2h = (half_t*)(ws + o); o += (size_t)R2c * 128 / 2;
    // fp16 x stream (16.8 MB) -- only if the workspace is big enough
    half_t* xhp = (half_t*)(ws + o);
    const size_t xh_floats = BTn * (size_t)DINn / 2;
    const int use_xh = (ws_size >= (o + xh_floats) * sizeof(float)) ? 1 : 0;

    k_stack<<<128, 256, 0, stream>>>(Wff1_0, bff1_0, Wff2_0, bff2_0, Wta_0, bta_0, Wtb_0, btb_0,
                                     mask_0, U0c, C0c, HPn, Wx0s, Wh0s, b0s);
    k_stack<<<64, 256, 0, stream>>>(Wff1_1, bff1_1, Wff2_1, bff2_1, Wta_1, bta_1, Wtb_1, btb_1,
                                    mask_1, U1c, C1c, C1c, W1s, W1s, b1s);
    k_stack<<<16, 256, 0, stream>>>(Wff1_2, bff1_2, Wff2_2, bff2_2, Wta_2, bta_2, Wtb_2, btb_2,
                                    mask_2, U2c, C2c, C2c, W2s, W2s, b2s);
    k_comb<<<R0c, DINn, 0, stream>>>(Wx0s, Wp, Wcb);
    k_biasc<<<32, 256, 0, stream>>>(Wx0s, bp, b0s, b0c, Wh2, Wh2T);
    k_pack<<<320, 256, 0, stream>>>(Wcb, Wh0s, W1s, W2s, W0h, W1h, W2h);
    if (use_xh) {
        k_xh<<<(int)(BTn * DINn / 4 / 256), 256, 0, stream>>>(x, xhp);
    }
    k_scan<<<BBn, 512, 0, stream>>>(W0h, W1h, W2h, b0c, b1s, b2s, x, xhp, use_xh,
                                    (float*)d_out);
    k_head<<<(int)(BTn / 256), 256, 0, stream>>>((float*)d_out, Wh1, bh1, Wh2T, bh2);
}